// Round 1
// baseline (233.605 us; speedup 1.0000x reference)
//
#include <hip/hip_runtime.h>

#define F16 _Float16
typedef __attribute__((ext_vector_type(8))) _Float16 half8;
typedef __attribute__((ext_vector_type(4))) float f32x4;

constexpr int S = 2048;
constexpr int E = 2048;
constexpr float MASK_NEG = -66504.0f;
constexpr float INV_SQRT_D = 0.08838834764831845f;  // 1/sqrt(128)

__device__ __forceinline__ void gload16(const void* g, void* l) {
  __builtin_amdgcn_global_load_lds((const __attribute__((address_space(1))) void*)g,
                                   (__attribute__((address_space(3))) void*)l, 16, 0, 0);
}

// ---------------- elementwise f32 -> f16 cast ----------------
__global__ __launch_bounds__(256) void cast_f32_f16_k(const float* __restrict__ x,
                                                      F16* __restrict__ y) {
  size_t i = ((size_t)blockIdx.x * 256 + threadIdx.x) * 8;
  float4 a = *(const float4*)(x + i);
  float4 b = *(const float4*)(x + i + 4);
  half8 h;
  h[0] = (F16)a.x; h[1] = (F16)a.y; h[2] = (F16)a.z; h[3] = (F16)a.w;
  h[4] = (F16)b.x; h[5] = (F16)b.y; h[6] = (F16)b.z; h[7] = (F16)b.w;
  *(half8*)(y + i) = h;
}

// ---------------- f32 [E][E] -> f16 transposed [E][E] ----------------
__global__ __launch_bounds__(256) void transpose_cast_k(const float* __restrict__ W,
                                                        F16* __restrict__ Wt) {
  __shared__ float tile[64][65];
  const int t = threadIdx.x;
  const int bx = blockIdx.x, by = blockIdx.y;
  {
    int r = t >> 4, c = (t & 15) << 2;
    const float* src = W + (size_t)(by * 64 + r) * E + bx * 64 + c;
    #pragma unroll
    for (int i = 0; i < 4; ++i) {
      float4 v = *(const float4*)(src + (size_t)i * 16 * E);
      tile[r + i * 16][c + 0] = v.x; tile[r + i * 16][c + 1] = v.y;
      tile[r + i * 16][c + 2] = v.z; tile[r + i * 16][c + 3] = v.w;
    }
  }
  __syncthreads();
  {
    int r = t >> 2, c = (t & 3) << 4;
    half8 v0, v1;
    #pragma unroll
    for (int i = 0; i < 8; ++i) v0[i] = (F16)tile[c + i][r];
    #pragma unroll
    for (int i = 0; i < 8; ++i) v1[i] = (F16)tile[c + 8 + i][r];
    F16* dst = Wt + (size_t)(bx * 64 + r) * E + by * 64 + c;
    *(half8*)dst = v0;
    *(half8*)(dst + 8) = v1;
  }
}

// ---------------- fp16 GEMM: C[M,N] = A[M,K] * Bt[N,K]^T ----------------
// M=N=K=2048, 128x128 tile, BK=64, 4 waves (2x2), XOR-swizzled LDS.
template <bool OUT_F32>
__global__ __launch_bounds__(256, 2) void gemm_bt_k(const F16* __restrict__ A,
                                                    const F16* __restrict__ Bt,
                                                    void* __restrict__ Cv) {
  constexpr int K = 2048, N = 2048;
  __shared__ F16 sA[128 * 64];
  __shared__ F16 sB[128 * 64];
  const int t = threadIdx.x;
  const int lane = t & 63, wave = t >> 6;
  const int wr = wave >> 1, wc = wave & 1;
  const int bm = blockIdx.y, bn = blockIdx.x;

  f32x4 acc[4][4];
  #pragma unroll
  for (int mi = 0; mi < 4; ++mi)
    #pragma unroll
    for (int ni = 0; ni < 4; ++ni) acc[mi][ni] = (f32x4){0.f, 0.f, 0.f, 0.f};

  // staging: linear LDS chunk (t + it*256)*16B; row = t/8 + it*32; byte-in-row = (t&7)*16
  const int rb = t >> 3;
  const int bofs = (t & 7) << 4;
  const int kOff = (bofs ^ ((rb & 7) << 4)) >> 1;  // pre-swizzled source k offset (elements)
  const F16* aSrc = A + (size_t)(bm * 128 + rb) * K + kOff;
  const F16* bSrc = Bt + (size_t)(bn * 128 + rb) * K + kOff;
  F16* aDst = sA + t * 8;
  F16* bDst = sB + t * 8;

  for (int bk = 0; bk < K; bk += 64) {
    #pragma unroll
    for (int it = 0; it < 4; ++it) {
      gload16(aSrc + (size_t)it * 32 * K + bk, aDst + it * 2048);
      gload16(bSrc + (size_t)it * 32 * K + bk, bDst + it * 2048);
    }
    __syncthreads();
    #pragma unroll
    for (int kk = 0; kk < 2; ++kk) {
      half8 af[4], bf[4];
      const int kb = kk * 64 + ((lane >> 4) << 4);
      #pragma unroll
      for (int i = 0; i < 4; ++i) {
        const int ra = wr * 64 + i * 16 + (lane & 15);
        af[i] = *(const half8*)((const char*)sA + ra * 128 + (kb ^ ((ra & 7) << 4)));
        const int rn = wc * 64 + i * 16 + (lane & 15);
        bf[i] = *(const half8*)((const char*)sB + rn * 128 + (kb ^ ((rn & 7) << 4)));
      }
      #pragma unroll
      for (int mi = 0; mi < 4; ++mi)
        #pragma unroll
        for (int ni = 0; ni < 4; ++ni)
          acc[mi][ni] = __builtin_amdgcn_mfma_f32_16x16x32_f16(af[mi], bf[ni], acc[mi][ni], 0, 0, 0);
    }
    __syncthreads();
  }

  #pragma unroll
  for (int mi = 0; mi < 4; ++mi) {
    const int r0 = bm * 128 + wr * 64 + mi * 16 + ((lane >> 4) << 2);
    #pragma unroll
    for (int ni = 0; ni < 4; ++ni) {
      const int c = bn * 128 + wc * 64 + ni * 16 + (lane & 15);
      #pragma unroll
      for (int j = 0; j < 4; ++j) {
        if (OUT_F32)
          ((float*)Cv)[(size_t)(r0 + j) * N + c] = acc[mi][ni][j];
        else
          ((F16*)Cv)[(size_t)(r0 + j) * N + c] = (F16)acc[mi][ni][j];
      }
    }
  }
}

// ---------------- flash attention (causal) ----------------
// Q,K: [S,E] f16 (head h at cols h*128..); Vt: [E,S] f16 (V transposed); O: [S,E] f16.
// Block: one (head, 64-row q-tile), 4 waves, each wave 16 q rows. KV tiles of 64.
__global__ __launch_bounds__(256, 2) void attn_fwd_k(const F16* __restrict__ Q,
                                                     const F16* __restrict__ Km,
                                                     const F16* __restrict__ Vt,
                                                     F16* __restrict__ O) {
  __shared__ F16 sK[64 * 128];  // [kv][d], 256B rows, swz (r&15)<<4
  __shared__ F16 sV[128 * 64];  // [d][kv], 128B rows, swz (r&7)<<4
  __shared__ F16 sP[64 * 64];   // [q][kv], 128B rows, swz (r&7)<<4
  const int t = threadIdx.x, lane = t & 63, w = t >> 6;
  const int h = blockIdx.x & 15, qt = blockIdx.x >> 4;
  const int qrow0 = qt * 64 + w * 16;

  half8 qf[4];
  {
    const int r = qrow0 + (lane & 15);
    const F16* qp = Q + (size_t)r * E + h * 128 + ((lane >> 4) << 3);
    #pragma unroll
    for (int kd = 0; kd < 4; ++kd) qf[kd] = *(const half8*)(qp + kd * 32);
  }

  f32x4 oacc[8];
  #pragma unroll
  for (int i = 0; i < 8; ++i) oacc[i] = (f32x4){0.f, 0.f, 0.f, 0.f};
  float mrow[4] = {-3e38f, -3e38f, -3e38f, -3e38f};
  float lrow[4] = {0.f, 0.f, 0.f, 0.f};

  const int rk = t >> 4;
  const int bkb = (t & 15) << 4;
  const int kcol = (bkb ^ ((rk & 15) << 4)) >> 1;  // d offset (elements)
  const int rv = t >> 3;
  const int bvb = (t & 7) << 4;
  const int vcol = (bvb ^ ((rv & 7) << 4)) >> 1;   // kv offset (elements)

  for (int kt = 0; kt <= qt; ++kt) {
    const F16* kSrc = Km + (size_t)(kt * 64 + rk) * E + h * 128 + kcol;
    const F16* vSrc = Vt + (size_t)(h * 128 + rv) * S + kt * 64 + vcol;
    #pragma unroll
    for (int it = 0; it < 4; ++it) {
      gload16(kSrc + (size_t)it * 16 * E, sK + t * 8 + it * 2048);
      gload16(vSrc + (size_t)it * 32 * S, sV + t * 8 + it * 2048);
    }
    __syncthreads();

    // scores: wave's 16 q rows x 64 kv
    f32x4 sacc[4];
    #pragma unroll
    for (int i = 0; i < 4; ++i) sacc[i] = (f32x4){0.f, 0.f, 0.f, 0.f};
    #pragma unroll
    for (int kd = 0; kd < 4; ++kd) {
      const int kb = kd * 64 + ((lane >> 4) << 4);
      #pragma unroll
      for (int ni = 0; ni < 4; ++ni) {
        const int rn = ni * 16 + (lane & 15);
        half8 bf = *(const half8*)((const char*)sK + rn * 256 + (kb ^ ((rn & 15) << 4)));
        sacc[ni] = __builtin_amdgcn_mfma_f32_16x16x32_f16(qf[kd], bf, sacc[ni], 0, 0, 0);
      }
    }

    const bool diag = (kt == qt);
    float pvv[4][4];
    const int qg0 = qrow0 + ((lane >> 4) << 2);
    const int kg0 = kt * 64 + (lane & 15);
    #pragma unroll
    for (int j = 0; j < 4; ++j) {
      float mx = -3e38f;
      #pragma unroll
      for (int ni = 0; ni < 4; ++ni) {
        float s = sacc[ni][j];
        if (diag && (kg0 + ni * 16) > (qg0 + j)) s += MASK_NEG;  // mask BEFORE scale, like ref
        s *= INV_SQRT_D;
        pvv[ni][j] = s;
        mx = fmaxf(mx, s);
      }
      mx = fmaxf(mx, __shfl_xor(mx, 1));
      mx = fmaxf(mx, __shfl_xor(mx, 2));
      mx = fmaxf(mx, __shfl_xor(mx, 4));
      mx = fmaxf(mx, __shfl_xor(mx, 8));
      const float mnew = fmaxf(mrow[j], mx);
      const float sc = __expf(mrow[j] - mnew);
      float rs = 0.f;
      #pragma unroll
      for (int ni = 0; ni < 4; ++ni) {
        const float p = __expf(pvv[ni][j] - mnew);
        pvv[ni][j] = p;
        rs += p;
      }
      rs += __shfl_xor(rs, 1);
      rs += __shfl_xor(rs, 2);
      rs += __shfl_xor(rs, 4);
      rs += __shfl_xor(rs, 8);
      lrow[j] = lrow[j] * sc + rs;
      mrow[j] = mnew;
      #pragma unroll
      for (int df = 0; df < 8; ++df) oacc[df][j] *= sc;
    }

    // P (f16) -> LDS in swizzled layout
    {
      const int rl0 = w * 16 + ((lane >> 4) << 2);
      #pragma unroll
      for (int ni = 0; ni < 4; ++ni) {
        const int cb = (ni * 16 + (lane & 15)) * 2;
        #pragma unroll
        for (int j = 0; j < 4; ++j) {
          const int r = rl0 + j;
          *(F16*)((char*)sP + r * 128 + (cb ^ ((r & 7) << 4))) = (F16)pvv[ni][j];
        }
      }
    }
    __syncthreads();

    // PV: oacc += P * V
    #pragma unroll
    for (int kk = 0; kk < 2; ++kk) {
      const int kb = kk * 64 + ((lane >> 4) << 4);
      const int ra = w * 16 + (lane & 15);
      half8 pa = *(const half8*)((const char*)sP + ra * 128 + (kb ^ ((ra & 7) << 4)));
      #pragma unroll
      for (int df = 0; df < 8; ++df) {
        const int rd = df * 16 + (lane & 15);
        half8 vf = *(const half8*)((const char*)sV + rd * 128 + (kb ^ ((rd & 7) << 4)));
        oacc[df] = __builtin_amdgcn_mfma_f32_16x16x32_f16(pa, vf, oacc[df], 0, 0, 0);
      }
    }
    __syncthreads();
  }

  #pragma unroll
  for (int j = 0; j < 4; ++j) {
    const float inv = 1.0f / lrow[j];
    const int r = qrow0 + ((lane >> 4) << 2) + j;
    F16* op = O + (size_t)r * E + h * 128 + (lane & 15);
    #pragma unroll
    for (int df = 0; df < 8; ++df) op[df * 16] = (F16)(oacc[df][j] * inv);
  }
}

// ---------------- launcher ----------------
extern "C" void kernel_launch(void* const* d_in, const int* in_sizes, int n_in,
                              void* d_out, int out_size, void* d_ws, size_t ws_size,
                              hipStream_t stream) {
  const float* X  = (const float*)d_in[0];
  const float* Wq = (const float*)d_in[1];
  const float* Wk = (const float*)d_in[2];
  const float* Wv = (const float*)d_in[3];
  const float* Wo = (const float*)d_in[4];
  float* out = (float*)d_out;

  const size_t MAT = (size_t)2048 * 2048;  // elements per 2048x2048 f16 matrix
  F16* Xh = (F16*)d_ws;      // X in f16              [S,E]
  F16* Wt = Xh + MAT;        // current W^T in f16    [E,E] (reused)
  F16* Qh = Wt + MAT;        // Q                     [S,E]
  F16* Kh = Qh + MAT;        // K                     [S,E]
  F16* Vh = Kh + MAT;        // V^T                   [E,S]
  F16* Ah = Vh + MAT;        // attn out (heads merged) [S,E]
  // total workspace use: 6 * 8 MiB = 48 MiB

  dim3 b256(256);
  cast_f32_f16_k<<<dim3(MAT / 2048), b256, 0, stream>>>(X, Xh);

  transpose_cast_k<<<dim3(32, 32), b256, 0, stream>>>(Wq, Wt);
  gemm_bt_k<false><<<dim3(16, 16), b256, 0, stream>>>(Xh, Wt, Qh);

  transpose_cast_k<<<dim3(32, 32), b256, 0, stream>>>(Wk, Wt);
  gemm_bt_k<false><<<dim3(16, 16), b256, 0, stream>>>(Xh, Wt, Kh);

  transpose_cast_k<<<dim3(32, 32), b256, 0, stream>>>(Wv, Wt);
  gemm_bt_k<false><<<dim3(16, 16), b256, 0, stream>>>(Wt, Xh, Vh);  // V^T = Wv^T * X^T

  attn_fwd_k<<<dim3(512), b256, 0, stream>>>(Qh, Kh, Vh, Ah);

  transpose_cast_k<<<dim3(32, 32), b256, 0, stream>>>(Wo, Wt);
  gemm_bt_k<true><<<dim3(16, 16), b256, 0, stream>>>(Ah, Wt, out);
}

// Round 2
// 196.220 us; speedup vs baseline: 1.1905x; 1.1905x over previous
//
#include <hip/hip_runtime.h>

#define F16 _Float16
typedef __attribute__((ext_vector_type(8))) _Float16 half8;
typedef __attribute__((ext_vector_type(4))) float f32x4;

constexpr int S = 2048;
constexpr int E = 2048;
constexpr float MASK_NEG = -66504.0f;
constexpr float INV_SQRT_D = 0.08838834764831845f;  // 1/sqrt(128)
constexpr float MASK_SC = MASK_NEG * INV_SQRT_D;    // mask applied to pre-scaled scores

__device__ __forceinline__ void gload16(const void* g, void* l) {
  __builtin_amdgcn_global_load_lds((const __attribute__((address_space(1))) void*)g,
                                   (__attribute__((address_space(3))) void*)l, 16, 0, 0);
}

// ---------------- elementwise f32 -> f16 cast ----------------
__global__ __launch_bounds__(256) void cast_f32_f16_k(const float* __restrict__ x,
                                                      F16* __restrict__ y) {
  size_t i = ((size_t)blockIdx.x * 256 + threadIdx.x) * 8;
  float4 a = *(const float4*)(x + i);
  float4 b = *(const float4*)(x + i + 4);
  half8 h;
  h[0] = (F16)a.x; h[1] = (F16)a.y; h[2] = (F16)a.z; h[3] = (F16)a.w;
  h[4] = (F16)b.x; h[5] = (F16)b.y; h[6] = (F16)b.z; h[7] = (F16)b.w;
  *(half8*)(y + i) = h;
}

// ---------------- dual f32 [E][E] -> f16 transposed [E][E] ----------------
__global__ __launch_bounds__(256) void transpose_cast2_k(const float* __restrict__ W0,
                                                         const float* __restrict__ W1,
                                                         F16* __restrict__ D0,
                                                         F16* __restrict__ D1) {
  const float* W = blockIdx.z ? W1 : W0;
  F16* Wt = blockIdx.z ? D1 : D0;
  __shared__ float tile[64][65];
  const int t = threadIdx.x;
  const int bx = blockIdx.x, by = blockIdx.y;
  {
    int r = t >> 4, c = (t & 15) << 2;
    const float* src = W + (size_t)(by * 64 + r) * E + bx * 64 + c;
    #pragma unroll
    for (int i = 0; i < 4; ++i) {
      float4 v = *(const float4*)(src + (size_t)i * 16 * E);
      tile[r + i * 16][c + 0] = v.x; tile[r + i * 16][c + 1] = v.y;
      tile[r + i * 16][c + 2] = v.z; tile[r + i * 16][c + 3] = v.w;
    }
  }
  __syncthreads();
  {
    int r = t >> 2, c = (t & 3) << 4;
    half8 v0, v1;
    #pragma unroll
    for (int i = 0; i < 8; ++i) v0[i] = (F16)tile[c + i][r];
    #pragma unroll
    for (int i = 0; i < 8; ++i) v1[i] = (F16)tile[c + 8 + i][r];
    F16* dst = Wt + (size_t)(bx * 64 + r) * E + by * 64 + c;
    *(half8*)dst = v0;
    *(half8*)(dst + 8) = v1;
  }
}

// ---------------- fp16 GEMM: C[M,N] = A[M,K] * Bt[N,K]^T ----------------
// MODE 0: single f16 out. MODE 1: fused QK (Bt has 4096 rows; bn<16 -> C0 scaled
// by 1/sqrt(D), else C1). MODE 2: f32 out.
template <int MODE>
__global__ __launch_bounds__(256, 2) void gemm_bt_k(const F16* __restrict__ A,
                                                    const F16* __restrict__ Bt,
                                                    void* __restrict__ C0v,
                                                    void* __restrict__ C1v) {
  constexpr int K = 2048, N = 2048;
  __shared__ F16 sA[128 * 64];
  __shared__ F16 sB[128 * 64];
  const int t = threadIdx.x;
  const int lane = t & 63, wave = t >> 6;
  const int wr = wave >> 1, wc = wave & 1;
  const int bm = blockIdx.y, bn = blockIdx.x;

  f32x4 acc[4][4];
  #pragma unroll
  for (int mi = 0; mi < 4; ++mi)
    #pragma unroll
    for (int ni = 0; ni < 4; ++ni) acc[mi][ni] = (f32x4){0.f, 0.f, 0.f, 0.f};

  const int rb = t >> 3;
  const int bofs = (t & 7) << 4;
  const int kOff = (bofs ^ ((rb & 7) << 4)) >> 1;
  const F16* aSrc = A + (size_t)(bm * 128 + rb) * K + kOff;
  const F16* bSrc = Bt + (size_t)(bn * 128 + rb) * K + kOff;
  F16* aDst = sA + t * 8;
  F16* bDst = sB + t * 8;

  for (int bk = 0; bk < K; bk += 64) {
    #pragma unroll
    for (int it = 0; it < 4; ++it) {
      gload16(aSrc + (size_t)it * 32 * K + bk, aDst + it * 2048);
      gload16(bSrc + (size_t)it * 32 * K + bk, bDst + it * 2048);
    }
    __syncthreads();
    #pragma unroll
    for (int kk = 0; kk < 2; ++kk) {
      half8 af[4], bf[4];
      const int kb = kk * 64 + ((lane >> 4) << 4);
      #pragma unroll
      for (int i = 0; i < 4; ++i) {
        const int ra = wr * 64 + i * 16 + (lane & 15);
        af[i] = *(const half8*)((const char*)sA + ra * 128 + (kb ^ ((ra & 7) << 4)));
        const int rn = wc * 64 + i * 16 + (lane & 15);
        bf[i] = *(const half8*)((const char*)sB + rn * 128 + (kb ^ ((rn & 7) << 4)));
      }
      #pragma unroll
      for (int mi = 0; mi < 4; ++mi)
        #pragma unroll
        for (int ni = 0; ni < 4; ++ni)
          acc[mi][ni] = __builtin_amdgcn_mfma_f32_16x16x32_f16(af[mi], bf[ni], acc[mi][ni], 0, 0, 0);
    }
    __syncthreads();
  }

  const float scale = (MODE == 1 && bn < 16) ? INV_SQRT_D : 1.0f;
  void* Cv = (MODE == 1 && bn >= 16) ? C1v : C0v;
  const int cb = (MODE == 1 ? (bn & 15) : bn) * 128;

  #pragma unroll
  for (int mi = 0; mi < 4; ++mi) {
    const int r0 = bm * 128 + wr * 64 + mi * 16 + ((lane >> 4) << 2);
    #pragma unroll
    for (int ni = 0; ni < 4; ++ni) {
      const int c = cb + wc * 64 + ni * 16 + (lane & 15);
      #pragma unroll
      for (int j = 0; j < 4; ++j) {
        if (MODE == 2)
          ((float*)Cv)[(size_t)(r0 + j) * N + c] = acc[mi][ni][j];
        else
          ((F16*)Cv)[(size_t)(r0 + j) * N + c] = (F16)(acc[mi][ni][j] * scale);
      }
    }
  }
}

// ---------------- flash attention (causal) ----------------
// Q pre-scaled by 1/sqrt(D). Q,K: [S,E] f16; Vt: [E,S] f16 (V transposed); O: [S,E].
// 512 blocks, qt DESCENDING (LPT). Double-buffered K/V, 1 barrier/iter.
__global__ __launch_bounds__(256, 2) void attn_fwd_k(const F16* __restrict__ Q,
                                                     const F16* __restrict__ Km,
                                                     const F16* __restrict__ Vt,
                                                     F16* __restrict__ O) {
  __shared__ F16 sK[2][64 * 128];  // [kv][d], 256B rows, swz (r&15)<<4
  __shared__ F16 sV[2][128 * 64];  // [d][kv], 128B rows, swz (r&7)<<4
  __shared__ F16 sP[64 * 64];      // [q][kv], wave-private rows
  const int t = threadIdx.x, lane = t & 63, w = t >> 6;
  const int h = blockIdx.x & 15, qt = 31 - (blockIdx.x >> 4);
  const int qrow0 = qt * 64 + w * 16;

  half8 qf[4];
  {
    const int r = qrow0 + (lane & 15);
    const F16* qp = Q + (size_t)r * E + h * 128 + ((lane >> 4) << 3);
    #pragma unroll
    for (int kd = 0; kd < 4; ++kd) qf[kd] = *(const half8*)(qp + kd * 32);
  }

  f32x4 oacc[8];
  #pragma unroll
  for (int i = 0; i < 8; ++i) oacc[i] = (f32x4){0.f, 0.f, 0.f, 0.f};
  float mrow[4] = {-3e38f, -3e38f, -3e38f, -3e38f};
  float lrow[4] = {0.f, 0.f, 0.f, 0.f};

  const int rk = t >> 4;
  const int kcol = (((t & 15) << 4) ^ ((rk & 15) << 4)) >> 1;  // d offset (elems)
  const int rv = t >> 3;
  const int vcol = (((t & 7) << 4) ^ ((rv & 7) << 4)) >> 1;    // kv offset (elems)
  const F16* kBase = Km + (size_t)rk * E + h * 128 + kcol;
  const F16* vBase = Vt + (size_t)(h * 128 + rv) * S + vcol;

  auto stage = [&](int kt, int b) {
    const F16* kSrc = kBase + (size_t)kt * 64 * E;
    const F16* vSrc = vBase + kt * 64;
    #pragma unroll
    for (int it = 0; it < 4; ++it) {
      gload16(kSrc + (size_t)it * 16 * E, &sK[b][t * 8 + it * 2048]);
      gload16(vSrc + (size_t)it * 32 * S, &sV[b][t * 8 + it * 2048]);
    }
  };

  stage(0, 0);

  for (int kt = 0; kt <= qt; ++kt) {
    __syncthreads();  // drains tile kt's loads; all waves done with buf being overwritten
    if (kt < qt) stage(kt + 1, (kt + 1) & 1);
    const char* bK = (const char*)sK[kt & 1];
    const char* bV = (const char*)sV[kt & 1];

    // scores: wave's 16 q rows x 64 kv (Q pre-scaled)
    f32x4 sacc[4];
    #pragma unroll
    for (int i = 0; i < 4; ++i) sacc[i] = (f32x4){0.f, 0.f, 0.f, 0.f};
    #pragma unroll
    for (int kd = 0; kd < 4; ++kd) {
      const int kb = kd * 64 + ((lane >> 4) << 4);
      #pragma unroll
      for (int ni = 0; ni < 4; ++ni) {
        const int rn = ni * 16 + (lane & 15);
        half8 bf = *(const half8*)(bK + rn * 256 + (kb ^ ((rn & 15) << 4)));
        sacc[ni] = __builtin_amdgcn_mfma_f32_16x16x32_f16(qf[kd], bf, sacc[ni], 0, 0, 0);
      }
    }

    const bool diag = (kt == qt);
    float pvv[4][4];
    const int qg0 = qrow0 + ((lane >> 4) << 2);
    const int kg0 = kt * 64 + (lane & 15);
    #pragma unroll
    for (int j = 0; j < 4; ++j) {
      float mx = -3e38f;
      #pragma unroll
      for (int ni = 0; ni < 4; ++ni) {
        float s = sacc[ni][j];
        if (diag && (kg0 + ni * 16) > (qg0 + j)) s += MASK_SC;
        pvv[ni][j] = s;
        mx = fmaxf(mx, s);
      }
      mx = fmaxf(mx, __shfl_xor(mx, 1));
      mx = fmaxf(mx, __shfl_xor(mx, 2));
      mx = fmaxf(mx, __shfl_xor(mx, 4));
      mx = fmaxf(mx, __shfl_xor(mx, 8));
      const float mnew = fmaxf(mrow[j], mx);
      const float sc = __expf(mrow[j] - mnew);
      float rs = 0.f;
      #pragma unroll
      for (int ni = 0; ni < 4; ++ni) {
        const float p = __expf(pvv[ni][j] - mnew);
        pvv[ni][j] = p;
        rs += p;
      }
      rs += __shfl_xor(rs, 1);
      rs += __shfl_xor(rs, 2);
      rs += __shfl_xor(rs, 4);
      rs += __shfl_xor(rs, 8);
      lrow[j] = lrow[j] * sc + rs;
      mrow[j] = mnew;
      #pragma unroll
      for (int df = 0; df < 8; ++df) oacc[df][j] *= sc;
    }

    // P (f16) -> LDS (wave-private rows; no barrier needed)
    {
      const int rl0 = w * 16 + ((lane >> 4) << 2);
      #pragma unroll
      for (int ni = 0; ni < 4; ++ni) {
        const int cb = (ni * 16 + (lane & 15)) * 2;
        #pragma unroll
        for (int j = 0; j < 4; ++j) {
          const int r = rl0 + j;
          *(F16*)((char*)sP + r * 128 + (cb ^ ((r & 7) << 4))) = (F16)pvv[ni][j];
        }
      }
    }

    // PV: oacc += P * V  (reads only this wave's sP rows)
    #pragma unroll
    for (int kk = 0; kk < 2; ++kk) {
      const int kb = kk * 64 + ((lane >> 4) << 4);
      const int ra = w * 16 + (lane & 15);
      half8 pa = *(const half8*)((const char*)sP + ra * 128 + (kb ^ ((ra & 7) << 4)));
      #pragma unroll
      for (int df = 0; df < 8; ++df) {
        const int rd = df * 16 + (lane & 15);
        half8 vf = *(const half8*)(bV + rd * 128 + (kb ^ ((rd & 7) << 4)));
        oacc[df] = __builtin_amdgcn_mfma_f32_16x16x32_f16(pa, vf, oacc[df], 0, 0, 0);
      }
    }
  }

  #pragma unroll
  for (int j = 0; j < 4; ++j) {
    const float inv = 1.0f / lrow[j];
    const int r = qrow0 + ((lane >> 4) << 2) + j;
    F16* op = O + (size_t)r * E + h * 128 + (lane & 15);
    #pragma unroll
    for (int df = 0; df < 8; ++df) op[df * 16] = (F16)(oacc[df][j] * inv);
  }
}

// ---------------- launcher ----------------
extern "C" void kernel_launch(void* const* d_in, const int* in_sizes, int n_in,
                              void* d_out, int out_size, void* d_ws, size_t ws_size,
                              hipStream_t stream) {
  const float* X  = (const float*)d_in[0];
  const float* Wq = (const float*)d_in[1];
  const float* Wk = (const float*)d_in[2];
  const float* Wv = (const float*)d_in[3];
  const float* Wo = (const float*)d_in[4];
  float* out = (float*)d_out;

  const size_t MAT = (size_t)2048 * 2048;
  F16* Xh  = (F16*)d_ws;     // X f16 [S,E]; later reused as attn output Ah
  F16* Wt0 = Xh + MAT;       // Wq^T, then Wv^T
  F16* Wt1 = Wt0 + MAT;      // Wk^T, then Wo^T
  F16* Qh  = Wt1 + MAT;      // Q (pre-scaled by 1/sqrt(D))
  F16* Kh  = Qh + MAT;       // K
  F16* Vh  = Kh + MAT;       // V^T [E,S]
  // workspace: 6 * 8 MiB = 48 MiB

  dim3 b256(256);
  cast_f32_f16_k<<<dim3(MAT / 2048), b256, 0, stream>>>(X, Xh);

  transpose_cast2_k<<<dim3(32, 32, 2), b256, 0, stream>>>(Wq, Wk, Wt0, Wt1);
  gemm_bt_k<1><<<dim3(32, 16), b256, 0, stream>>>(Xh, Wt0, Qh, Kh);   // Q (scaled), K

  transpose_cast2_k<<<dim3(32, 32, 2), b256, 0, stream>>>(Wv, Wo, Wt0, Wt1);
  gemm_bt_k<0><<<dim3(16, 16), b256, 0, stream>>>(Wt0, Xh, Vh, nullptr);  // V^T = Wv^T X^T

  attn_fwd_k<<<dim3(512), b256, 0, stream>>>(Qh, Kh, Vh, Xh);  // attn out -> Xh

  gemm_bt_k<2><<<dim3(16, 16), b256, 0, stream>>>(Xh, Wt1, out, nullptr);
}